// Round 1
// baseline (355.113 us; speedup 1.0000x reference)
//
#include <hip/hip_runtime.h>
#include <hip/hip_bf16.h>
#include <math.h>

// Problem constants (B=1)
#define A_    16
#define SK_   2048
#define SQ_   2048
#define D_    128
#define IDM_  128
#define R_    3
#define NROW_ (A_ * SK_)   // 32768 rows per tensor (K or Q)

// Workspace layout (float offsets). Total = 208,992 floats ≈ 836 KB.
#define WS_VK 0            // [A][R][D]  = 6144
#define WS_VQ 6144         // [A][R][D]  = 6144
#define WS_CK 12288        // [A][R]     = 48
#define WS_CQ 12336        // [A][R]     = 48
#define WS_KC 12384        // [R][A*SK]  = 98304   (plane-major for coalescing)
#define WS_QC 110688       // [R][A*SQ]  = 98304

// ---------------------------------------------------------------------------
// Kernel A: fold the uplift linear layer into the hash projection.
//   VK[a,r,d] = sum_e Wk[e,d] * W[a,e,r]      cK[a,r] = sum_e bk[e] * W[a,e,r]
// grid = 2*A*R = 96 blocks, 128 threads (thread = d). Trivial cost.
// ---------------------------------------------------------------------------
__global__ void fuse_weights_kernel(const float* __restrict__ Wk,
                                    const float* __restrict__ bk,
                                    const float* __restrict__ Wq,
                                    const float* __restrict__ bq,
                                    const float* __restrict__ W,
                                    float* __restrict__ ws) {
    int bid = blockIdx.x;                  // 0..95
    int isQ = (bid >= A_ * R_) ? 1 : 0;
    int ar  = isQ ? bid - A_ * R_ : bid;
    int a = ar / R_;
    int r = ar % R_;
    const float* Wm = isQ ? Wq : Wk;
    const float* bm = isQ ? bq : bk;
    int d = threadIdx.x;                   // 0..127
    float acc = 0.f, cacc = 0.f;
    for (int e = 0; e < IDM_; ++e) {
        float w = W[(a * IDM_ + e) * R_ + r];   // broadcast across lanes
        acc  += Wm[e * D_ + d] * w;             // coalesced
        cacc += bm[e] * w;
    }
    float* V = ws + (isQ ? WS_VQ : WS_VK);
    V[(a * R_ + r) * D_ + d] = acc;
    if (d == 0) ws[(isQ ? WS_CQ : WS_CK) + a * R_ + r] = cacc;
}

// ---------------------------------------------------------------------------
// Kernel B: codes.  Kc[a,s,r] = tanh((K[a,s,:] . VK[a,r,:] + cK[a,r]) / 10)
// One thread per row; 256 blocks x 256 threads. Blocks 0..127 -> K rows,
// 128..255 -> Q rows. Each block's 256 rows share one head 'a'
// (2048 % 256 == 0), so VK[a] (+bias) is staged once in LDS.
// ---------------------------------------------------------------------------
__global__ void codes_kernel(const float* __restrict__ K,
                             const float* __restrict__ Q,
                             float* __restrict__ ws) {
    __shared__ __align__(16) float sV[R_][D_];
    __shared__ float sc[R_];
    int blk = blockIdx.x;                   // 0..255
    int isQ = (blk >= 128) ? 1 : 0;
    int rowBase = (isQ ? blk - 128 : blk) * 256;   // in [0, 32768)
    int a = rowBase >> 11;                  // /2048
    const float* V = ws + (isQ ? WS_VQ : WS_VK) + a * R_ * D_;
    const float* c = ws + (isQ ? WS_CQ : WS_CK) + a * R_;
    int tid = threadIdx.x;
    for (int i = tid; i < R_ * D_; i += 256) sV[i / D_][i % D_] = V[i];
    if (tid < R_) sc[tid] = c[tid];
    __syncthreads();

    int row = rowBase + tid;
    const float4* row4 = ((const float4*)(isQ ? Q : K)) + (size_t)row * (D_ / 4);
    float a0 = 0.f, a1 = 0.f, a2 = 0.f;
    const float4* v0p = (const float4*)sV[0];
    const float4* v1p = (const float4*)sV[1];
    const float4* v2p = (const float4*)sV[2];
#pragma unroll 8
    for (int d4 = 0; d4 < D_ / 4; ++d4) {
        float4 x  = row4[d4];
        float4 v0 = v0p[d4];   // LDS broadcast (all lanes same addr)
        float4 v1 = v1p[d4];
        float4 v2 = v2p[d4];
        a0 += x.x * v0.x + x.y * v0.y + x.z * v0.z + x.w * v0.w;
        a1 += x.x * v1.x + x.y * v1.y + x.z * v1.z + x.w * v1.w;
        a2 += x.x * v2.x + x.y * v2.y + x.z * v2.z + x.w * v2.w;
    }
    float* codes = ws + (isQ ? WS_QC : WS_KC);
    codes[0 * NROW_ + row] = tanhf((a0 + sc[0]) * 0.1f);   // coalesced stores
    codes[1 * NROW_ + row] = tanhf((a1 + sc[1]) * 0.1f);
    codes[2 * NROW_ + row] = tanhf((a2 + sc[2]) * 0.1f);
}

// ---------------------------------------------------------------------------
// Kernel C: the 256 MB streaming map.
//   out[a,t,s] = g( (Kc0[s]Qc0[t] + Kc1[s]Qc1[t] + Kc2[s]Qc2[t]) / 3 )
//   g(p) = p * sigmoid(p/10) ~= p*(0.5 + 0.025p)   (|err| <= 2.1e-5 for |p|<=1)
// Block tile: 1024 s x 64 t. 256 threads; thread i owns s = s0+4i..+3 (float4).
// Qc tile (3x64 floats) in LDS, broadcast-read. Stores fully coalesced.
// grid = (SK/1024=2, SQ/64=32, A=16) = 1024 blocks, 256 KB written each.
// ---------------------------------------------------------------------------
__global__ void pc_kernel(const float* __restrict__ ws, float* __restrict__ out) {
    const int TT = 64;
    int a  = blockIdx.z;
    int t0 = blockIdx.y * TT;
    int s0 = blockIdx.x * 1024;
    __shared__ float sQ[R_][TT];
    int tid = threadIdx.x;                  // 0..255
    if (tid < R_ * TT) {
        int r = tid / TT, t = tid % TT;
        sQ[r][t] = ws[WS_QC + r * NROW_ + a * SQ_ + t0 + t];
    }
    __syncthreads();

    int s = s0 + tid * 4;
    const float* kc = ws + WS_KC + a * SK_;
    float4 k0 = *(const float4*)(kc + 0 * NROW_ + s);
    float4 k1 = *(const float4*)(kc + 1 * NROW_ + s);
    float4 k2 = *(const float4*)(kc + 2 * NROW_ + s);

    float4* ob = (float4*)out;
    size_t rowBase = ((size_t)(a * SQ_ + t0) * SK_ + s) >> 2;   // float4 index
    const float third = 1.0f / 3.0f;
#pragma unroll 4
    for (int t = 0; t < TT; ++t) {
        float q0 = sQ[0][t], q1 = sQ[1][t], q2 = sQ[2][t];
        float4 o;
        float p;
        p = (k0.x * q0 + k1.x * q1 + k2.x * q2) * third; o.x = p * (0.5f + 0.025f * p);
        p = (k0.y * q0 + k1.y * q1 + k2.y * q2) * third; o.y = p * (0.5f + 0.025f * p);
        p = (k0.z * q0 + k1.z * q1 + k2.z * q2) * third; o.z = p * (0.5f + 0.025f * p);
        p = (k0.w * q0 + k1.w * q1 + k2.w * q2) * third; o.w = p * (0.5f + 0.025f * p);
        ob[rowBase + (size_t)t * (SK_ / 4)] = o;
    }
}

extern "C" void kernel_launch(void* const* d_in, const int* in_sizes, int n_in,
                              void* d_out, int out_size, void* d_ws, size_t ws_size,
                              hipStream_t stream) {
    const float* K  = (const float*)d_in[0];
    const float* Q  = (const float*)d_in[1];
    const float* Wk = (const float*)d_in[2];
    const float* bk = (const float*)d_in[3];
    const float* Wq = (const float*)d_in[4];
    const float* bq = (const float*)d_in[5];
    const float* W  = (const float*)d_in[6];
    float* out = (float*)d_out;
    float* ws  = (float*)d_ws;

    fuse_weights_kernel<<<2 * A_ * R_, 128, 0, stream>>>(Wk, bk, Wq, bq, W, ws);
    codes_kernel<<<256, 256, 0, stream>>>(K, Q, ws);
    dim3 grid(SK_ / 1024, SQ_ / 64, A_);
    pc_kernel<<<grid, 256, 0, stream>>>(ws, out);
}

// Round 3
// 312.835 us; speedup vs baseline: 1.1351x; 1.1351x over previous
//
#include <hip/hip_runtime.h>
#include <hip/hip_bf16.h>
#include <math.h>

// Problem constants (B=1)
#define A_    16
#define SK_   2048
#define SQ_   2048
#define D_    128
#define IDM_  128
#define R_    3
#define NROW_ (A_ * SK_)   // 32768 rows per tensor (K or Q)

// Workspace layout (float offsets). Total = 208,992 floats ~= 836 KB.
#define WS_VK 0            // [A][R][D]  = 6144
#define WS_VQ 6144         // [A][R][D]  = 6144
#define WS_CK 12288        // [A][R]     = 48
#define WS_CQ 12336        // [A][R]     = 48
#define WS_KC 12384        // [R][A*SK]  = 98304   (plane-major for coalescing)
#define WS_QC 110688       // [R][A*SQ]  = 98304

// native vector type for nontemporal stores (HIP float4 is a struct and
// __builtin_nontemporal_store rejects it)
typedef float nt4 __attribute__((ext_vector_type(4)));

// ---------------------------------------------------------------------------
// Kernel A: fold the uplift linear layer into the hash projection.
//   VK[a,r,d] = sum_e Wk[e,d] * W[a,e,r]      cK[a,r] = sum_e bk[e] * W[a,e,r]
// grid = 2*A*R = 96 blocks, 128 threads (thread = d). Trivial cost.
// ---------------------------------------------------------------------------
__global__ void fuse_weights_kernel(const float* __restrict__ Wk,
                                    const float* __restrict__ bk,
                                    const float* __restrict__ Wq,
                                    const float* __restrict__ bq,
                                    const float* __restrict__ W,
                                    float* __restrict__ ws) {
    int bid = blockIdx.x;                  // 0..95
    int isQ = (bid >= A_ * R_) ? 1 : 0;
    int ar  = isQ ? bid - A_ * R_ : bid;
    int a = ar / R_;
    int r = ar % R_;
    const float* Wm = isQ ? Wq : Wk;
    const float* bm = isQ ? bq : bk;
    int d = threadIdx.x;                   // 0..127
    float acc = 0.f, cacc = 0.f;
#pragma unroll 8
    for (int e = 0; e < IDM_; ++e) {
        float w = W[(a * IDM_ + e) * R_ + r];   // broadcast across lanes
        acc  += Wm[e * D_ + d] * w;             // coalesced
        cacc += bm[e] * w;
    }
    float* V = ws + (isQ ? WS_VQ : WS_VK);
    V[(a * R_ + r) * D_ + d] = acc;
    if (d == 0) ws[(isQ ? WS_CQ : WS_CK) + a * R_ + r] = cacc;
}

// ---------------------------------------------------------------------------
// Kernel B: codes.  Kc[a,s,r] = tanh((K[a,s,:] . VK[a,r,:] + cK[a,r]) / 10)
// COALESCED version: each 32-lane half-group owns one row; lane l holds
// row[4l..4l+3] (full wave reads 1 KB contiguous). 3 dots reduced with
// __shfl_xor butterflies. 1024 blocks x 256 threads; block = 64 rows
// (8 rows/pass x 8 passes), all in one head (64 | 2048).
// Blocks 0..511 -> K rows, 512..1023 -> Q rows.
// ---------------------------------------------------------------------------
__global__ void codes_kernel(const float* __restrict__ K,
                             const float* __restrict__ Q,
                             float* __restrict__ ws) {
    __shared__ __align__(16) float sV[R_][D_];
    __shared__ float sc[R_];
    int blk = blockIdx.x;                   // 0..1023
    int isQ = (blk >= 512) ? 1 : 0;
    int rowBase = (isQ ? blk - 512 : blk) * 64;    // in [0, 32768)
    int a = rowBase >> 11;                  // /2048
    const float* V = ws + (isQ ? WS_VQ : WS_VK) + a * R_ * D_;
    const float* c = ws + (isQ ? WS_CQ : WS_CK) + a * R_;
    int tid = threadIdx.x;
    for (int i = tid; i < R_ * D_; i += 256) sV[i / D_][i % D_] = V[i];
    if (tid < R_) sc[tid] = c[tid];
    __syncthreads();

    int sub  = tid >> 5;                    // 0..7 : row group within pass
    int lane = tid & 31;                    // 0..31: element group within row
    const float* src = isQ ? Q : K;
    float* codes = ws + (isQ ? WS_QC : WS_KC);
    // lane's slice of the projection vectors (registers, from LDS once)
    float4 v0 = ((const float4*)sV[0])[lane];
    float4 v1 = ((const float4*)sV[1])[lane];
    float4 v2 = ((const float4*)sV[2])[lane];
    float bias = (lane < R_) ? sc[lane] : 0.f;

#pragma unroll
    for (int pass = 0; pass < 8; ++pass) {
        int row = rowBase + pass * 8 + sub;
        float4 x = ((const float4*)(src + (size_t)row * D_))[lane];
        float a0 = x.x * v0.x + x.y * v0.y + x.z * v0.z + x.w * v0.w;
        float a1 = x.x * v1.x + x.y * v1.y + x.z * v1.z + x.w * v1.w;
        float a2 = x.x * v2.x + x.y * v2.y + x.z * v2.z + x.w * v2.w;
#pragma unroll
        for (int off = 16; off >= 1; off >>= 1) {
            a0 += __shfl_xor(a0, off, 32);
            a1 += __shfl_xor(a1, off, 32);
            a2 += __shfl_xor(a2, off, 32);
        }
        if (lane < R_) {
            float v = (lane == 0) ? a0 : (lane == 1) ? a1 : a2;
            codes[lane * NROW_ + row] = tanhf((v + bias) * 0.1f);
        }
    }
}

// ---------------------------------------------------------------------------
// Kernel C: the 256 MB streaming map.
//   out[a,t,s] = g( (Kc0[s]Qc0[t] + Kc1[s]Qc1[t] + Kc2[s]Qc2[t]) / 3 )
//   g(p) = p * sigmoid(p/10) ~= p*(0.5 + 0.025p)   (|err| <= 2.1e-5 for |p|<=1)
// The 1/3 is folded into the LDS Qc tile. Block tile: 1024 s x 32 t.
// 256 threads; thread i owns s = s0+4i..+3 (float4), nontemporal stores.
// grid = (2, 64, 16) = 2048 blocks -> 8 blocks/CU, 32 waves/CU.
// ---------------------------------------------------------------------------
__global__ __launch_bounds__(256)
void pc_kernel(const float* __restrict__ ws, float* __restrict__ out) {
    const int TT = 32;
    int a  = blockIdx.z;
    int t0 = blockIdx.y * TT;
    int s0 = blockIdx.x * 1024;
    __shared__ float sQ[R_][TT];
    int tid = threadIdx.x;                  // 0..255
    if (tid < R_ * TT) {
        int r = tid >> 5, t = tid & 31;
        sQ[r][t] = ws[WS_QC + r * NROW_ + a * SQ_ + t0 + t] * (1.0f / 3.0f);
    }
    __syncthreads();

    int s = s0 + tid * 4;
    const float* kc = ws + WS_KC + a * SK_;
    float4 k0 = *(const float4*)(kc + 0 * NROW_ + s);
    float4 k1 = *(const float4*)(kc + 1 * NROW_ + s);
    float4 k2 = *(const float4*)(kc + 2 * NROW_ + s);

    nt4* op = (nt4*)out + (((size_t)(a * SQ_ + t0) * SK_ + s) >> 2);
#pragma unroll 4
    for (int t = 0; t < TT; ++t) {
        float q0 = sQ[0][t], q1 = sQ[1][t], q2 = sQ[2][t];
        nt4 o;
        float p;
        p = k0.x * q0 + k1.x * q1 + k2.x * q2; o.x = p * (0.5f + 0.025f * p);
        p = k0.y * q0 + k1.y * q1 + k2.y * q2; o.y = p * (0.5f + 0.025f * p);
        p = k0.z * q0 + k1.z * q1 + k2.z * q2; o.z = p * (0.5f + 0.025f * p);
        p = k0.w * q0 + k1.w * q1 + k2.w * q2; o.w = p * (0.5f + 0.025f * p);
        __builtin_nontemporal_store(o, op);
        op += SK_ / 4;
    }
}

extern "C" void kernel_launch(void* const* d_in, const int* in_sizes, int n_in,
                              void* d_out, int out_size, void* d_ws, size_t ws_size,
                              hipStream_t stream) {
    const float* K  = (const float*)d_in[0];
    const float* Q  = (const float*)d_in[1];
    const float* Wk = (const float*)d_in[2];
    const float* bk = (const float*)d_in[3];
    const float* Wq = (const float*)d_in[4];
    const float* bq = (const float*)d_in[5];
    const float* W  = (const float*)d_in[6];
    float* out = (float*)d_out;
    float* ws  = (float*)d_ws;

    fuse_weights_kernel<<<2 * A_ * R_, 128, 0, stream>>>(Wk, bk, Wq, bq, W, ws);
    codes_kernel<<<1024, 256, 0, stream>>>(K, Q, ws);
    dim3 grid(SK_ / 1024, SQ_ / 32, A_);
    pc_kernel<<<grid, 256, 0, stream>>>(ws, out);
}

// Round 4
// 308.641 us; speedup vs baseline: 1.1506x; 1.0136x over previous
//
#include <hip/hip_runtime.h>
#include <hip/hip_bf16.h>
#include <math.h>

// Problem constants (B=1)
#define A_    16
#define SK_   2048
#define SQ_   2048
#define D_    128
#define IDM_  128
#define R_    3
#define NROW_ (A_ * SK_)   // 32768 rows per tensor (K or Q)

// Workspace layout (float offsets). Total = 208,992 floats ~= 836 KB.
#define WS_VK 0            // [A][R][D]  = 6144
#define WS_VQ 6144         // [A][R][D]  = 6144
#define WS_CK 12288        // [A][R]     = 48
#define WS_CQ 12336        // [A][R]     = 48
#define WS_KC 12384        // [R][A*SK]  = 98304   (plane-major for coalescing)
#define WS_QC 110688       // [R][A*SQ]  = 98304

// native vector type for nontemporal stores (HIP float4 is a struct and
// __builtin_nontemporal_store rejects it)
typedef float nt4 __attribute__((ext_vector_type(4)));

// ---------------------------------------------------------------------------
// Kernel A: fold the uplift linear layer into the hash projection.
//   VK[a,r,d] = sum_e Wk[e,d] * W[a,e,r]      cK[a,r] = sum_e bk[e] * W[a,e,r]
// grid = 2*A*R = 96 blocks, 128 threads (thread = d). Trivial cost.
// ---------------------------------------------------------------------------
__global__ void fuse_weights_kernel(const float* __restrict__ Wk,
                                    const float* __restrict__ bk,
                                    const float* __restrict__ Wq,
                                    const float* __restrict__ bq,
                                    const float* __restrict__ W,
                                    float* __restrict__ ws) {
    int bid = blockIdx.x;                  // 0..95
    int isQ = (bid >= A_ * R_) ? 1 : 0;
    int ar  = isQ ? bid - A_ * R_ : bid;
    int a = ar / R_;
    int r = ar % R_;
    const float* Wm = isQ ? Wq : Wk;
    const float* bm = isQ ? bq : bk;
    int d = threadIdx.x;                   // 0..127
    float acc = 0.f, cacc = 0.f;
#pragma unroll 8
    for (int e = 0; e < IDM_; ++e) {
        float w = W[(a * IDM_ + e) * R_ + r];   // broadcast across lanes
        acc  += Wm[e * D_ + d] * w;             // coalesced
        cacc += bm[e] * w;
    }
    float* V = ws + (isQ ? WS_VQ : WS_VK);
    V[(a * R_ + r) * D_ + d] = acc;
    if (d == 0) ws[(isQ ? WS_CQ : WS_CK) + a * R_ + r] = cacc;
}

// ---------------------------------------------------------------------------
// Kernel B: codes.  Kc[a,s,r] = tanh((K[a,s,:] . VK[a,r,:] + cK[a,r]) / 10)
// Each 32-lane half-group owns one row; lane l holds row[4l..4l+3] (full
// wave reads 1 KB contiguous). 3 dots reduced with __shfl_xor butterflies.
// 1024 blocks x 256 threads; block = 64 rows, all in one head.
// Blocks 0..511 -> K rows, 512..1023 -> Q rows.
// ---------------------------------------------------------------------------
__global__ void codes_kernel(const float* __restrict__ K,
                             const float* __restrict__ Q,
                             float* __restrict__ ws) {
    __shared__ __align__(16) float sV[R_][D_];
    __shared__ float sc[R_];
    int blk = blockIdx.x;                   // 0..1023
    int isQ = (blk >= 512) ? 1 : 0;
    int rowBase = (isQ ? blk - 512 : blk) * 64;    // in [0, 32768)
    int a = rowBase >> 11;                  // /2048
    const float* V = ws + (isQ ? WS_VQ : WS_VK) + a * R_ * D_;
    const float* c = ws + (isQ ? WS_CQ : WS_CK) + a * R_;
    int tid = threadIdx.x;
    for (int i = tid; i < R_ * D_; i += 256) sV[i / D_][i % D_] = V[i];
    if (tid < R_) sc[tid] = c[tid];
    __syncthreads();

    int sub  = tid >> 5;                    // 0..7 : row group within pass
    int lane = tid & 31;                    // 0..31: element group within row
    const float* src = isQ ? Q : K;
    float* codes = ws + (isQ ? WS_QC : WS_KC);
    // lane's slice of the projection vectors (registers, from LDS once)
    float4 v0 = ((const float4*)sV[0])[lane];
    float4 v1 = ((const float4*)sV[1])[lane];
    float4 v2 = ((const float4*)sV[2])[lane];
    float bias = (lane < R_) ? sc[lane] : 0.f;

#pragma unroll
    for (int pass = 0; pass < 8; ++pass) {
        int row = rowBase + pass * 8 + sub;
        float4 x = ((const float4*)(src + (size_t)row * D_))[lane];
        float a0 = x.x * v0.x + x.y * v0.y + x.z * v0.z + x.w * v0.w;
        float a1 = x.x * v1.x + x.y * v1.y + x.z * v1.z + x.w * v1.w;
        float a2 = x.x * v2.x + x.y * v2.y + x.z * v2.z + x.w * v2.w;
#pragma unroll
        for (int off = 16; off >= 1; off >>= 1) {
            a0 += __shfl_xor(a0, off, 32);
            a1 += __shfl_xor(a1, off, 32);
            a2 += __shfl_xor(a2, off, 32);
        }
        if (lane < R_) {
            float v = (lane == 0) ? a0 : (lane == 1) ? a1 : a2;
            codes[lane * NROW_ + row] = tanhf((v + bias) * 0.1f);
        }
    }
}

// ---------------------------------------------------------------------------
// Kernel C: the 256 MB streaming map.
//   out[a,t,s] = g( (Kc0[s]Qc0[t] + Kc1[s]Qc1[t] + Kc2[s]Qc2[t]) / 3 )
//   g(p) = p * sigmoid(p/10) ~= p*(0.5 + 0.025p)   (|err| <= 2.1e-5 for |p|<=1)
// 1/3 folded into the Qc LDS tile, which is packed as float4 (R padded to 4)
// so each t-iteration is ONE broadcast ds_read_b128 instead of 3 scalar
// reads. Block tile: 1024 s x 32 t; thread owns one float4 of s; NT stores;
// full unroll 8 for store-queue depth. grid = 2048 blocks = 8/CU, 32 waves/CU.
// ---------------------------------------------------------------------------
__global__ __launch_bounds__(256)
void pc_kernel(const float* __restrict__ ws, float* __restrict__ out) {
    const int TT = 32;
    int a  = blockIdx.z;
    int t0 = blockIdx.y * TT;
    int s0 = blockIdx.x * 1024;
    __shared__ __align__(16) float4 sQ[TT];   // (q0,q1,q2,0) * 1/3
    int tid = threadIdx.x;                  // 0..255
    if (tid < TT) {
        int qb = WS_QC + a * SQ_ + t0 + tid;
        sQ[tid] = make_float4(ws[qb + 0 * NROW_] * (1.0f / 3.0f),
                              ws[qb + 1 * NROW_] * (1.0f / 3.0f),
                              ws[qb + 2 * NROW_] * (1.0f / 3.0f), 0.f);
    }
    __syncthreads();

    int s = s0 + tid * 4;
    const float* kc = ws + WS_KC + a * SK_;
    float4 k0 = *(const float4*)(kc + 0 * NROW_ + s);
    float4 k1 = *(const float4*)(kc + 1 * NROW_ + s);
    float4 k2 = *(const float4*)(kc + 2 * NROW_ + s);

    nt4* op = (nt4*)out + (((size_t)(a * SQ_ + t0) * SK_ + s) >> 2);
#pragma unroll 8
    for (int t = 0; t < TT; ++t) {
        float4 q = sQ[t];                   // one ds_read_b128, broadcast
        nt4 o;
        float p;
        p = k0.x * q.x + k1.x * q.y + k2.x * q.z; o.x = p * (0.5f + 0.025f * p);
        p = k0.y * q.x + k1.y * q.y + k2.y * q.z; o.y = p * (0.5f + 0.025f * p);
        p = k0.z * q.x + k1.z * q.y + k2.z * q.z; o.z = p * (0.5f + 0.025f * p);
        p = k0.w * q.x + k1.w * q.y + k2.w * q.z; o.w = p * (0.5f + 0.025f * p);
        __builtin_nontemporal_store(o, op);
        op += SK_ / 4;
    }
}

extern "C" void kernel_launch(void* const* d_in, const int* in_sizes, int n_in,
                              void* d_out, int out_size, void* d_ws, size_t ws_size,
                              hipStream_t stream) {
    const float* K  = (const float*)d_in[0];
    const float* Q  = (const float*)d_in[1];
    const float* Wk = (const float*)d_in[2];
    const float* bk = (const float*)d_in[3];
    const float* Wq = (const float*)d_in[4];
    const float* bq = (const float*)d_in[5];
    const float* W  = (const float*)d_in[6];
    float* out = (float*)d_out;
    float* ws  = (float*)d_ws;

    fuse_weights_kernel<<<2 * A_ * R_, 128, 0, stream>>>(Wk, bk, Wq, bq, W, ws);
    codes_kernel<<<1024, 256, 0, stream>>>(K, Q, ws);
    dim3 grid(SK_ / 1024, SQ_ / 32, A_);
    pc_kernel<<<grid, 256, 0, stream>>>(ws, out);
}